// Round 4
// baseline (646.117 us; speedup 1.0000x reference)
//
#include <hip/hip_runtime.h>
#include <hip/hip_bf16.h>

// Problem constants
#define BGR   256                 // graphs
#define NPG1  512                 // nodes per graph (input)
#define DEG   16
#define EPG   (NPG1 * DEG)        // 8192 edges per graph
#define LB    5                   // lookback features
#define DIM   64
#define OUTF  6
#define NN    (BGR * NPG1)        // 131,072
#define K1    410                 // ceil(0.8*512)
#define K2    328                 // ceil(0.8*410)
#define N1    (BGR * K1)          // 104,960

// ---------------------------------------------------------------------------
// Stage 1 (one block per graph, 512 threads = 8 waves)
__global__ __launch_bounds__(512)
void stage1_kernel(const float* __restrict__ x,
                   const int* __restrict__ eidx,
                   const float* __restrict__ Wl,
                   const float* __restrict__ bl,
                   const float* __restrict__ Wr,
                   const float* __restrict__ pw,
                   float* __restrict__ h1p,
                   int* __restrict__ invr,
                   float* __restrict__ x1buf) {
    __shared__ __align__(16) float xl[NPG1 * LB];      // 10 KB raw features
    __shared__ __align__(16) float sums[NPG1 * LB];    // 10 KB aggregation
    __shared__ int   degi[NPG1];
    __shared__ __align__(16) float sc[NPG1];
    __shared__ int   rnk[NPG1];
    __shared__ float redmx[8 * DIM];
    __shared__ float redsm[8 * DIM];

    const int g = blockIdx.x, t = threadIdx.x;
    const int wid = t >> 6, lane = t & 63;
    const int* __restrict__ src = eidx;
    const int* __restrict__ dst = eidx + (BGR * EPG);

    {   // vectorized staging + zero (2560 floats = 640 float4)
        const float4* x4 = (const float4*)(x + (size_t)g * (NPG1 * LB));
        float4* xl4 = (float4*)xl;
        float4* sm4 = (float4*)sums;
        const float4 z4 = make_float4(0.f, 0.f, 0.f, 0.f);
        #pragma unroll
        for (int k = 0; k < 2; ++k) {
            int i = k * 512 + t;
            if (i < NPG1 * LB / 4) { xl4[i] = x4[i]; sm4[i] = z4; }
        }
        degi[t] = 0;
    }
    __syncthreads();

    // Edge aggregation into LDS (native float LDS atomics)
    const int ebase = g * EPG;
    #pragma unroll 4
    for (int k = 0; k < EPG / 512; ++k) {
        int e = ebase + k * 512 + t;
        int s = src[e] & (NPG1 - 1);     // local ids (offsets are g*512)
        int d = dst[e] & (NPG1 - 1);
        #pragma unroll
        for (int j = 0; j < LB; ++j)
            unsafeAtomicAdd(&sums[d * LB + j], xl[s * LB + j]);
        atomicAdd(&degi[d], 1);
    }
    __syncthreads();

    float wlv[LB], wrv[LB];
    #pragma unroll
    for (int j = 0; j < LB; ++j) { wlv[j] = Wl[j * DIM + lane]; wrv[j] = Wr[j * DIM + lane]; }
    const float blv = bl[lane], pwv = pw[lane];
    float q = pwv * pwv;
    #pragma unroll
    for (int o = 32; o; o >>= 1) q += __shfl_xor(q, o);
    const float inv_nrm = 1.f / sqrtf(q);

    // Pass 1: scores (wave per node, lane = dim)
    for (int n = wid; n < NPG1; n += 8) {
        float invd = 1.f / fmaxf((float)degi[n], 1.f);
        float al = 0.f, ar = 0.f;
        #pragma unroll
        for (int j = 0; j < LB; ++j) {
            al += sums[n * LB + j] * wlv[j];
            ar += xl[n * LB + j] * wrv[j];
        }
        float acc = fmaxf(blv + al * invd + ar, 0.f);
        float p = acc * pwv;
        #pragma unroll
        for (int o = 32; o; o >>= 1) p += __shfl_xor(p, o);
        if (lane == 0) sc[n] = tanhf(p * inv_nrm);
    }
    __syncthreads();

    // Exact ranks (descending, ties -> lower index), pipelined float4 reads
    {
        float my = sc[t];
        int r = 0;
        const float4* sc4 = (const float4*)sc;
        #pragma unroll 4
        for (int j4 = 0; j4 < NPG1 / 4; ++j4) {
            float4 v = sc4[j4];
            int j = 4 * j4;
            r += (v.x > my) | ((v.x == my) & (j     < t));
            r += (v.y > my) | ((v.y == my) & (j + 1 < t));
            r += (v.z > my) | ((v.z == my) & (j + 2 < t));
            r += (v.w > my) | ((v.w == my) & (j + 3 < t));
        }
        rnk[t] = r;
        invr[g * NPG1 + t] = (r < K1) ? r : -1;
    }
    __syncthreads();

    // Pass 2: recompute kept rows, write scaled, readout accum
    float mx = -INFINITY, sm = 0.f;
    for (int n = wid; n < NPG1; n += 8) {
        int r = rnk[n];
        if (r >= K1) continue;
        float invd = 1.f / fmaxf((float)degi[n], 1.f);
        float al = 0.f, ar = 0.f;
        #pragma unroll
        for (int j = 0; j < LB; ++j) {
            al += sums[n * LB + j] * wlv[j];
            ar += xl[n * LB + j] * wrv[j];
        }
        float acc = fmaxf(blv + al * invd + ar, 0.f);
        float v = acc * sc[n];
        h1p[((size_t)g * K1 + r) * DIM + lane] = v;
        mx = fmaxf(mx, v);
        sm += v;
    }
    redmx[wid * DIM + lane] = mx;
    redsm[wid * DIM + lane] = sm;
    __syncthreads();
    if (wid == 0) {
        float m2 = redmx[lane], s2 = redsm[lane];
        #pragma unroll
        for (int w = 1; w < 8; ++w) {
            m2 = fmaxf(m2, redmx[w * DIM + lane]);
            s2 += redsm[w * DIM + lane];
        }
        x1buf[g * 2 * DIM + lane]       = m2;
        x1buf[g * 2 * DIM + DIM + lane] = s2 * (1.0f / (float)K1);
    }
}

// ---------------------------------------------------------------------------
// Stage 2 (one block per graph, 512 threads = 8 waves):
// filter+compact -> LDS aggregation -> weights->LDS (overlay on elist) ->
// conv2 4-nodes/wave-group -> topk2 -> readout2 -> fused MLP -> out.
__global__ __launch_bounds__(512)
void stage2_kernel(const int* __restrict__ eidx,
                   const int* __restrict__ invr,
                   const float* __restrict__ h1p,
                   const float* __restrict__ Wl,
                   const float* __restrict__ bl,
                   const float* __restrict__ Wr,
                   const float* __restrict__ pw,
                   const float* __restrict__ x1buf,
                   const float* __restrict__ W1,
                   const float* __restrict__ b1,
                   const float* __restrict__ W2,
                   const float* __restrict__ b2,
                   float* __restrict__ out) {
    __shared__ __align__(16) float sums2[(K1 + 1) * DIM];   // 105,216 B (+dummy row)
    __shared__ __align__(16) int   elist[EPG];              // 32,768 B; reused for Wl|Wr
    __shared__ int   deg2i[K1 + 1];
    __shared__ __align__(16) float sc2[412];                // K1 + 2 sentinel pad
    __shared__ int   rnk2[K1];
    __shared__ float redmx[8 * DIM];
    __shared__ float redsm[8 * DIM];
    __shared__ float zy[2 * DIM + DIM];                     // z (128) | y (64)
    __shared__ int   cnt;

    const int g = blockIdx.x, t = threadIdx.x;
    const int wid = t >> 6, lane = t & 63;
    const int* __restrict__ src = eidx;
    const int* __restrict__ dst = eidx + (BGR * EPG);
    const float* __restrict__ hg = h1p + (size_t)g * K1 * DIM;

    for (int i = t; i < (K1 + 1) * DIM; i += 512) sums2[i] = 0.f;
    if (t < K1 + 1) deg2i[t] = 0;
    if (t >= K1 && t < 412) sc2[t] = -INFINITY;             // rank-loop sentinels
    if (t == 0) cnt = 0;
    __syncthreads();

    // Filter edges via inv map; ballot-compact (rs,rd) pairs into LDS
    const int ebase = g * EPG;
    for (int k = 0; k < EPG / 512; ++k) {
        int e = ebase + k * 512 + t;
        int rs = invr[src[e]];
        int rd = invr[dst[e]];
        bool valid = (rs >= 0) && (rd >= 0);
        unsigned long long m = __ballot(valid);
        int base = 0;
        if (lane == 0 && m) base = atomicAdd(&cnt, __popcll(m));
        base = __shfl(base, 0);
        if (valid) {
            int pos = base + __popcll(m & ((1ull << lane) - 1ull));
            elist[pos] = (rs << 16) | rd;
            atomicAdd(&deg2i[rd], 1);
        }
    }
    __syncthreads();
    const int nv  = cnt;
    const int nvp = (nv + 63) & ~63;
    for (int i = nv + t; i < nvp; i += 512) elist[i] = K1;  // dummy: rs=0, rd=K1
    __syncthreads();

    // Aggregate h1p[src] rows into LDS — 8 independent loads in flight
    for (int i = wid * 8; i < nvp; i += 64) {
        int4 a = *(const int4*)&elist[i];
        int4 b = *(const int4*)&elist[i + 4];
        float v0 = hg[(a.x >> 16) * DIM + lane];
        float v1 = hg[(a.y >> 16) * DIM + lane];
        float v2 = hg[(a.z >> 16) * DIM + lane];
        float v3 = hg[(a.w >> 16) * DIM + lane];
        float v4 = hg[(b.x >> 16) * DIM + lane];
        float v5 = hg[(b.y >> 16) * DIM + lane];
        float v6 = hg[(b.z >> 16) * DIM + lane];
        float v7 = hg[(b.w >> 16) * DIM + lane];
        unsafeAtomicAdd(&sums2[(a.x & 0xffff) * DIM + lane], v0);
        unsafeAtomicAdd(&sums2[(a.y & 0xffff) * DIM + lane], v1);
        unsafeAtomicAdd(&sums2[(a.z & 0xffff) * DIM + lane], v2);
        unsafeAtomicAdd(&sums2[(a.w & 0xffff) * DIM + lane], v3);
        unsafeAtomicAdd(&sums2[(b.x & 0xffff) * DIM + lane], v4);
        unsafeAtomicAdd(&sums2[(b.y & 0xffff) * DIM + lane], v5);
        unsafeAtomicAdd(&sums2[(b.z & 0xffff) * DIM + lane], v6);
        unsafeAtomicAdd(&sums2[(b.w & 0xffff) * DIM + lane], v7);
    }
    __syncthreads();   // elist fully consumed; safe to overlay weights

    // Stage Wl,Wr into LDS (row-major [j][d]); consecutive-lane reads are
    // conflict-free. 32 KB, exactly elist's footprint.
    float* wl_s = (float*)elist;
    float* wr_s = wl_s + DIM * DIM;
    for (int i = t; i < DIM * DIM; i += 512) {
        wl_s[i] = Wl[i];
        wr_s[i] = Wr[i];
    }
    const float blv = bl[lane], pwv = pw[lane];
    float q = pwv * pwv;
    #pragma unroll
    for (int o = 32; o; o >>= 1) q += __shfl_xor(q, o);
    const float inv_nrm = 1.f / sqrtf(q);
    __syncthreads();

    // conv2: 4 nodes per wave-group; weights from LDS (amortized x4),
    // mean rows via LDS b128 broadcast, x rows via L2-hot global b128.
    for (int gi = wid; gi < (K1 + 3) / 4; gi += 8) {
        const int n0 = gi * 4;
        const int nA = n0;
        const int nB = (n0 + 1 < K1) ? n0 + 1 : K1 - 1;
        const int nC = (n0 + 2 < K1) ? n0 + 2 : K1 - 1;
        const int nD = (n0 + 3 < K1) ? n0 + 3 : K1 - 1;
        const float4* mA = (const float4*)&sums2[nA * DIM];
        const float4* mB = (const float4*)&sums2[nB * DIM];
        const float4* mC = (const float4*)&sums2[nC * DIM];
        const float4* mD = (const float4*)&sums2[nD * DIM];
        const float4* xA = (const float4*)&hg[(size_t)nA * DIM];
        const float4* xB = (const float4*)&hg[(size_t)nB * DIM];
        const float4* xC = (const float4*)&hg[(size_t)nC * DIM];
        const float4* xD = (const float4*)&hg[(size_t)nD * DIM];
        float lAa = 0.f, lBa = 0.f, lCa = 0.f, lDa = 0.f;
        float rAa = 0.f, rBa = 0.f, rCa = 0.f, rDa = 0.f;
        #pragma unroll 2
        for (int j4 = 0; j4 < DIM / 4; ++j4) {
            const int jb = 4 * j4 * DIM + lane;
            float w0 = wl_s[jb],           w1 = wl_s[jb + DIM];
            float w2 = wl_s[jb + 2 * DIM], w3 = wl_s[jb + 3 * DIM];
            float u0 = wr_s[jb],           u1 = wr_s[jb + DIM];
            float u2 = wr_s[jb + 2 * DIM], u3 = wr_s[jb + 3 * DIM];
            float4 a = mA[j4], b = mB[j4], c = mC[j4], d = mD[j4];
            float4 p = xA[j4], s = xB[j4], e = xC[j4], f = xD[j4];
            lAa += a.x * w0 + a.y * w1 + a.z * w2 + a.w * w3;
            lBa += b.x * w0 + b.y * w1 + b.z * w2 + b.w * w3;
            lCa += c.x * w0 + c.y * w1 + c.z * w2 + c.w * w3;
            lDa += d.x * w0 + d.y * w1 + d.z * w2 + d.w * w3;
            rAa += p.x * u0 + p.y * u1 + p.z * u2 + p.w * u3;
            rBa += s.x * u0 + s.y * u1 + s.z * u2 + s.w * u3;
            rCa += e.x * u0 + e.y * u1 + e.z * u2 + e.w * u3;
            rDa += f.x * u0 + f.y * u1 + f.z * u2 + f.w * u3;
        }
        float iA = 1.f / fmaxf((float)deg2i[nA], 1.f);
        float iB = 1.f / fmaxf((float)deg2i[nB], 1.f);
        float iC = 1.f / fmaxf((float)deg2i[nC], 1.f);
        float iD = 1.f / fmaxf((float)deg2i[nD], 1.f);
        float hA = fmaxf(blv + lAa * iA + rAa, 0.f);
        float hB = fmaxf(blv + lBa * iB + rBa, 0.f);
        float hC = fmaxf(blv + lCa * iC + rCa, 0.f);
        float hD = fmaxf(blv + lDa * iD + rDa, 0.f);
        float pA = hA * pwv, pB = hB * pwv, pC = hC * pwv, pD = hD * pwv;
        #pragma unroll
        for (int o = 32; o; o >>= 1) {
            pA += __shfl_xor(pA, o); pB += __shfl_xor(pB, o);
            pC += __shfl_xor(pC, o); pD += __shfl_xor(pD, o);
        }
        sums2[nA * DIM + lane] = hA;
        if (lane == 0) sc2[nA] = tanhf(pA * inv_nrm);
        if (n0 + 1 < K1) {
            sums2[nB * DIM + lane] = hB;
            if (lane == 0) sc2[nB] = tanhf(pB * inv_nrm);
        }
        if (n0 + 2 < K1) {
            sums2[nC * DIM + lane] = hC;
            if (lane == 0) sc2[nC] = tanhf(pC * inv_nrm);
        }
        if (n0 + 3 < K1) {
            sums2[nD * DIM + lane] = hD;
            if (lane == 0) sc2[nD] = tanhf(pD * inv_nrm);
        }
    }
    __syncthreads();

    // Ranks over K1 scores (sentinel-padded, pipelined float4 reads)
    if (t < K1) {
        float my = sc2[t];
        int r = 0;
        const float4* sc4 = (const float4*)sc2;
        #pragma unroll 4
        for (int j4 = 0; j4 < 103; ++j4) {
            float4 v = sc4[j4];
            int j = 4 * j4;
            r += (v.x > my) | ((v.x == my) & (j     < t));
            r += (v.y > my) | ((v.y == my) & (j + 1 < t));
            r += (v.z > my) | ((v.z == my) & (j + 2 < t));
            r += (v.w > my) | ((v.w == my) & (j + 3 < t));
        }
        rnk2[t] = r;
    }
    __syncthreads();

    // Readout over kept (rank < K2) scaled rows
    float mx = -INFINITY, sm = 0.f;
    for (int n = wid; n < K1; n += 8) {
        if (rnk2[n] < K2) {
            float v = sums2[n * DIM + lane] * sc2[n];
            mx = fmaxf(mx, v);
            sm += v;
        }
    }
    redmx[wid * DIM + lane] = mx;
    redsm[wid * DIM + lane] = sm;
    __syncthreads();
    if (wid == 0) {
        float m2 = redmx[lane], s2 = redsm[lane];
        #pragma unroll
        for (int w = 1; w < 8; ++w) {
            m2 = fmaxf(m2, redmx[w * DIM + lane]);
            s2 += redsm[w * DIM + lane];
        }
        zy[lane]       = x1buf[g * 2 * DIM + lane]       + m2;
        zy[DIM + lane] = x1buf[g * 2 * DIM + DIM + lane] + s2 * (1.0f / (float)K2);
    }
    __syncthreads();

    // Final MLP: y = relu(z@W1 + b1); out = y@W2 + b2
    if (t < DIM) {
        float a = b1[t];
        #pragma unroll 8
        for (int j = 0; j < 2 * DIM; ++j) a += zy[j] * W1[j * DIM + t];
        zy[2 * DIM + t] = fmaxf(a, 0.f);
    }
    __syncthreads();
    if (t < OUTF) {
        float a = b2[t];
        #pragma unroll
        for (int j = 0; j < DIM; ++j) a += zy[2 * DIM + j] * W2[j * OUTF + t];
        out[g * OUTF + t] = a;
    }
}

// ---------------------------------------------------------------------------
extern "C" void kernel_launch(void* const* d_in, const int* in_sizes, int n_in,
                              void* d_out, int out_size, void* d_ws, size_t ws_size,
                              hipStream_t stream) {
    (void)in_sizes; (void)n_in; (void)out_size; (void)ws_size;
    const float* x       = (const float*)d_in[0];
    const int*   eidx    = (const int*)d_in[1];
    const float* c1_Wl   = (const float*)d_in[2];
    const float* c1_bl   = (const float*)d_in[3];
    const float* c1_Wr   = (const float*)d_in[4];
    const float* pool1_w = (const float*)d_in[5];
    const float* c2_Wl   = (const float*)d_in[6];
    const float* c2_bl   = (const float*)d_in[7];
    const float* c2_Wr   = (const float*)d_in[8];
    const float* pool2_w = (const float*)d_in[9];
    const float* lin1_W  = (const float*)d_in[10];
    const float* lin1_b  = (const float*)d_in[11];
    const float* lin2_W  = (const float*)d_in[12];
    const float* lin2_b  = (const float*)d_in[13];
    float* out = (float*)d_out;

    // Workspace layout (256-aligned)
    char* w = (char*)d_ws;
    size_t off = 0;
    auto alloc = [&](size_t bytes) {
        void* p = w + off;
        off = (off + bytes + 255) & ~(size_t)255;
        return p;
    };
    float* h1p   = (float*)alloc((size_t)N1 * DIM * 4);      // 26.9 MB
    int*   invr  = (int*)  alloc((size_t)NN * 4);            // 512 KB
    float* x1buf = (float*)alloc((size_t)BGR * 2 * DIM * 4); // 128 KB

    stage1_kernel<<<BGR, 512, 0, stream>>>(x, eidx, c1_Wl, c1_bl, c1_Wr,
                                           pool1_w, h1p, invr, x1buf);
    stage2_kernel<<<BGR, 512, 0, stream>>>(eidx, invr, h1p, c2_Wl, c2_bl, c2_Wr,
                                           pool2_w, x1buf, lin1_W, lin1_b,
                                           lin2_W, lin2_b, out);
}

// Round 5
// 291.845 us; speedup vs baseline: 2.2139x; 2.2139x over previous
//
#include <hip/hip_runtime.h>
#include <hip/hip_bf16.h>

// Problem constants
#define BGR   256                 // graphs
#define NPG1  512                 // nodes per graph (input)
#define DEG   16
#define EPG   (NPG1 * DEG)        // 8192 edges per graph
#define LB    5                   // lookback features
#define DIM   64
#define OUTF  6
#define NN    (BGR * NPG1)        // 131,072
#define EDG   (BGR * EPG)         // 2,097,152
#define K1    410                 // ceil(0.8*512)
#define K2    328                 // ceil(0.8*410)
#define N1    (BGR * K1)          // 104,960
#define CSRW  64                  // CSR slots per node (max in-degree ~40)

// ---------------------------------------------------------------------------
// Stage 1 (one block per graph, 512 threads = 8 waves) — unchanged from R4.
__global__ __launch_bounds__(512)
void stage1_kernel(const float* __restrict__ x,
                   const int* __restrict__ eidx,
                   const float* __restrict__ Wl,
                   const float* __restrict__ bl,
                   const float* __restrict__ Wr,
                   const float* __restrict__ pw,
                   float* __restrict__ h1p,
                   int* __restrict__ invr,
                   float* __restrict__ x1buf) {
    __shared__ __align__(16) float xl[NPG1 * LB];
    __shared__ __align__(16) float sums[NPG1 * LB];
    __shared__ int   degi[NPG1];
    __shared__ __align__(16) float sc[NPG1];
    __shared__ int   rnk[NPG1];
    __shared__ float redmx[8 * DIM];
    __shared__ float redsm[8 * DIM];

    const int g = blockIdx.x, t = threadIdx.x;
    const int wid = t >> 6, lane = t & 63;
    const int* __restrict__ src = eidx;
    const int* __restrict__ dst = eidx + EDG;

    {
        const float4* x4 = (const float4*)(x + (size_t)g * (NPG1 * LB));
        float4* xl4 = (float4*)xl;
        float4* sm4 = (float4*)sums;
        const float4 z4 = make_float4(0.f, 0.f, 0.f, 0.f);
        #pragma unroll
        for (int k = 0; k < 2; ++k) {
            int i = k * 512 + t;
            if (i < NPG1 * LB / 4) { xl4[i] = x4[i]; sm4[i] = z4; }
        }
        degi[t] = 0;
    }
    __syncthreads();

    const int ebase = g * EPG;
    #pragma unroll 4
    for (int k = 0; k < EPG / 512; ++k) {
        int e = ebase + k * 512 + t;
        int s = src[e] & (NPG1 - 1);
        int d = dst[e] & (NPG1 - 1);
        #pragma unroll
        for (int j = 0; j < LB; ++j)
            unsafeAtomicAdd(&sums[d * LB + j], xl[s * LB + j]);
        atomicAdd(&degi[d], 1);
    }
    __syncthreads();

    float wlv[LB], wrv[LB];
    #pragma unroll
    for (int j = 0; j < LB; ++j) { wlv[j] = Wl[j * DIM + lane]; wrv[j] = Wr[j * DIM + lane]; }
    const float blv = bl[lane], pwv = pw[lane];
    float q = pwv * pwv;
    #pragma unroll
    for (int o = 32; o; o >>= 1) q += __shfl_xor(q, o);
    const float inv_nrm = 1.f / sqrtf(q);

    for (int n = wid; n < NPG1; n += 8) {
        float invd = 1.f / fmaxf((float)degi[n], 1.f);
        float al = 0.f, ar = 0.f;
        #pragma unroll
        for (int j = 0; j < LB; ++j) {
            al += sums[n * LB + j] * wlv[j];
            ar += xl[n * LB + j] * wrv[j];
        }
        float acc = fmaxf(blv + al * invd + ar, 0.f);
        float p = acc * pwv;
        #pragma unroll
        for (int o = 32; o; o >>= 1) p += __shfl_xor(p, o);
        if (lane == 0) sc[n] = tanhf(p * inv_nrm);
    }
    __syncthreads();

    {
        float my = sc[t];
        int r = 0;
        const float4* sc4 = (const float4*)sc;
        #pragma unroll 4
        for (int j4 = 0; j4 < NPG1 / 4; ++j4) {
            float4 v = sc4[j4];
            int j = 4 * j4;
            r += (v.x > my) | ((v.x == my) & (j     < t));
            r += (v.y > my) | ((v.y == my) & (j + 1 < t));
            r += (v.z > my) | ((v.z == my) & (j + 2 < t));
            r += (v.w > my) | ((v.w == my) & (j + 3 < t));
        }
        rnk[t] = r;
        invr[g * NPG1 + t] = (r < K1) ? r : -1;
    }
    __syncthreads();

    float mx = -INFINITY, sm = 0.f;
    for (int n = wid; n < NPG1; n += 8) {
        int r = rnk[n];
        if (r >= K1) continue;
        float invd = 1.f / fmaxf((float)degi[n], 1.f);
        float al = 0.f, ar = 0.f;
        #pragma unroll
        for (int j = 0; j < LB; ++j) {
            al += sums[n * LB + j] * wlv[j];
            ar += xl[n * LB + j] * wrv[j];
        }
        float acc = fmaxf(blv + al * invd + ar, 0.f);
        float v = acc * sc[n];
        h1p[((size_t)g * K1 + r) * DIM + lane] = v;
        mx = fmaxf(mx, v);
        sm += v;
    }
    redmx[wid * DIM + lane] = mx;
    redsm[wid * DIM + lane] = sm;
    __syncthreads();
    if (wid == 0) {
        float m2 = redmx[lane], s2 = redsm[lane];
        #pragma unroll
        for (int w = 1; w < 8; ++w) {
            m2 = fmaxf(m2, redmx[w * DIM + lane]);
            s2 += redsm[w * DIM + lane];
        }
        x1buf[g * 2 * DIM + lane]       = m2;
        x1buf[g * 2 * DIM + DIM + lane] = s2 * (1.0f / (float)K1);
    }
}

// ---------------------------------------------------------------------------
// CSR fill: edge-parallel, full occupancy. One native int atomic per valid
// edge; store global pooled src id into the dst node's CSR row.
__global__ __launch_bounds__(256)
void csr_fill_kernel(const int* __restrict__ eidx,
                     const int* __restrict__ invr,
                     int* __restrict__ csr,
                     int* __restrict__ indeg) {
    int e = blockIdx.x * 256 + threadIdx.x;       // grid = EDG/256 exact
    int s = eidx[e];
    int d = eidx[EDG + e];
    int rs = invr[s];
    int rd = invr[d];
    if ((rs | rd) < 0) return;                    // either dropped
    int g = s >> 9;                               // src = g*512 + local
    int gn = g * K1 + rd;                         // global pooled dst id
    int slot = atomicAdd(&indeg[gn], 1);
    csr[(size_t)gn * CSRW + slot] = g * K1 + rs;  // global pooled src id
}

// ---------------------------------------------------------------------------
// conv2 fused: 4 nodes per wave, 8 waves (32 nodes) per block; atomic-free
// register gather + mean, GEMV with LDS weights, h2 + score out.
// LDS = 40 KB -> 4 blocks/CU.
__global__ __launch_bounds__(512)
void conv2_kernel(const float* __restrict__ h1p,
                  const int* __restrict__ csr,
                  const int* __restrict__ indeg,
                  const float* __restrict__ Wl,
                  const float* __restrict__ bl,
                  const float* __restrict__ Wr,
                  const float* __restrict__ pw,
                  float* __restrict__ h2,
                  float* __restrict__ sc2g) {
    __shared__ __align__(16) float wls[DIM * DIM];      // 16 KB
    __shared__ __align__(16) float wrs[DIM * DIM];      // 16 KB
    __shared__ __align__(16) float mstage[8][4][DIM];   // 8 KB

    const int t = threadIdx.x, wid = t >> 6, lane = t & 63;
    for (int i = t; i < DIM * DIM; i += 512) { wls[i] = Wl[i]; wrs[i] = Wr[i]; }

    const float blv = bl[lane], pwv = pw[lane];
    float qq = pwv * pwv;
    #pragma unroll
    for (int o = 32; o; o >>= 1) qq += __shfl_xor(qq, o);
    const float inv_nrm = 1.f / sqrtf(qq);

    const int n0 = (blockIdx.x * 8 + wid) * 4;    // grid = N1/32 exact
    const int nA = n0, nB = n0 + 1, nC = n0 + 2, nD = n0 + 3;

    int dgA = indeg[nA], dgB = indeg[nB], dgC = indeg[nC], dgD = indeg[nD];
    int dgmax = max(max(dgA, dgB), max(dgC, dgD));
    const int4* cA = (const int4*)&csr[(size_t)nA * CSRW];
    const int4* cB = (const int4*)&csr[(size_t)nB * CSRW];
    const int4* cC = (const int4*)&csr[(size_t)nC * CSRW];
    const int4* cD = (const int4*)&csr[(size_t)nD * CSRW];

    float aA = 0.f, aB = 0.f, aC = 0.f, aD = 0.f;
    for (int kc = 0; 4 * kc < dgmax; ++kc) {
        int4 iA = cA[kc], iB = cB[kc], iC = cC[kc], iD = cD[kc];
        int k0 = 4 * kc;
        // clamp ids beyond degree to self (always-valid row), predicate the add
        #define GACC(acc, idv, kk, dg, nself)                              \
        {   int   _id = ((kk) < (dg)) ? (idv) : (nself);                   \
            float _v  = h1p[(size_t)_id * DIM + lane];                     \
            acc += ((kk) < (dg)) ? _v : 0.f; }
        GACC(aA, iA.x, k0,     dgA, nA) GACC(aA, iA.y, k0 + 1, dgA, nA)
        GACC(aA, iA.z, k0 + 2, dgA, nA) GACC(aA, iA.w, k0 + 3, dgA, nA)
        GACC(aB, iB.x, k0,     dgB, nB) GACC(aB, iB.y, k0 + 1, dgB, nB)
        GACC(aB, iB.z, k0 + 2, dgB, nB) GACC(aB, iB.w, k0 + 3, dgB, nB)
        GACC(aC, iC.x, k0,     dgC, nC) GACC(aC, iC.y, k0 + 1, dgC, nC)
        GACC(aC, iC.z, k0 + 2, dgC, nC) GACC(aC, iC.w, k0 + 3, dgC, nC)
        GACC(aD, iD.x, k0,     dgD, nD) GACC(aD, iD.y, k0 + 1, dgD, nD)
        GACC(aD, iD.z, k0 + 2, dgD, nD) GACC(aD, iD.w, k0 + 3, dgD, nD)
        #undef GACC
    }

    // mean -> per-wave LDS stage (same-wave write/read; no barrier needed)
    mstage[wid][0][lane] = aA * (1.f / fmaxf((float)dgA, 1.f));
    mstage[wid][1][lane] = aB * (1.f / fmaxf((float)dgB, 1.f));
    mstage[wid][2][lane] = aC * (1.f / fmaxf((float)dgC, 1.f));
    mstage[wid][3][lane] = aD * (1.f / fmaxf((float)dgD, 1.f));
    __syncthreads();   // weights staged (covers wls/wrs for all waves)

    const float4* mA = (const float4*)&mstage[wid][0][0];
    const float4* mB = (const float4*)&mstage[wid][1][0];
    const float4* mC = (const float4*)&mstage[wid][2][0];
    const float4* mD = (const float4*)&mstage[wid][3][0];
    const float4* xA = (const float4*)&h1p[(size_t)nA * DIM];
    const float4* xB = (const float4*)&h1p[(size_t)nB * DIM];
    const float4* xC = (const float4*)&h1p[(size_t)nC * DIM];
    const float4* xD = (const float4*)&h1p[(size_t)nD * DIM];

    float lA = 0.f, lB = 0.f, lC = 0.f, lD = 0.f;
    float rA = 0.f, rB = 0.f, rC = 0.f, rD = 0.f;
    #pragma unroll 2
    for (int j4 = 0; j4 < DIM / 4; ++j4) {
        const int jb = 4 * j4 * DIM + lane;
        float w0 = wls[jb],           w1 = wls[jb + DIM];
        float w2 = wls[jb + 2 * DIM], w3 = wls[jb + 3 * DIM];
        float u0 = wrs[jb],           u1 = wrs[jb + DIM];
        float u2 = wrs[jb + 2 * DIM], u3 = wrs[jb + 3 * DIM];
        float4 a = mA[j4], b = mB[j4], c = mC[j4], d = mD[j4];
        float4 p = xA[j4], s = xB[j4], e = xC[j4], f = xD[j4];
        lA += a.x * w0 + a.y * w1 + a.z * w2 + a.w * w3;
        lB += b.x * w0 + b.y * w1 + b.z * w2 + b.w * w3;
        lC += c.x * w0 + c.y * w1 + c.z * w2 + c.w * w3;
        lD += d.x * w0 + d.y * w1 + d.z * w2 + d.w * w3;
        rA += p.x * u0 + p.y * u1 + p.z * u2 + p.w * u3;
        rB += s.x * u0 + s.y * u1 + s.z * u2 + s.w * u3;
        rC += e.x * u0 + e.y * u1 + e.z * u2 + e.w * u3;
        rD += f.x * u0 + f.y * u1 + f.z * u2 + f.w * u3;
    }
    float hA = fmaxf(blv + lA + rA, 0.f);
    float hB = fmaxf(blv + lB + rB, 0.f);
    float hC = fmaxf(blv + lC + rC, 0.f);
    float hD = fmaxf(blv + lD + rD, 0.f);
    h2[(size_t)nA * DIM + lane] = hA;
    h2[(size_t)nB * DIM + lane] = hB;
    h2[(size_t)nC * DIM + lane] = hC;
    h2[(size_t)nD * DIM + lane] = hD;
    float pA = hA * pwv, pB = hB * pwv, pC = hC * pwv, pD = hD * pwv;
    #pragma unroll
    for (int o = 32; o; o >>= 1) {
        pA += __shfl_xor(pA, o); pB += __shfl_xor(pB, o);
        pC += __shfl_xor(pC, o); pD += __shfl_xor(pD, o);
    }
    if (lane == 0) {
        sc2g[nA] = tanhf(pA * inv_nrm);
        sc2g[nB] = tanhf(pB * inv_nrm);
        sc2g[nC] = tanhf(pC * inv_nrm);
        sc2g[nD] = tanhf(pD * inv_nrm);
    }
}

// ---------------------------------------------------------------------------
// Pool2 + readout2 + final MLP (one block per graph).
__global__ __launch_bounds__(512)
void pool2_mlp_kernel(const float* __restrict__ sc2g,
                      const float* __restrict__ h2,
                      const float* __restrict__ x1buf,
                      const float* __restrict__ W1,
                      const float* __restrict__ b1,
                      const float* __restrict__ W2,
                      const float* __restrict__ b2,
                      float* __restrict__ out) {
    __shared__ __align__(16) float sc2[412];
    __shared__ int   rnk2[K1];
    __shared__ float redmx[8 * DIM];
    __shared__ float redsm[8 * DIM];
    __shared__ float zy[2 * DIM + DIM];

    const int g = blockIdx.x, t = threadIdx.x;
    const int wid = t >> 6, lane = t & 63;

    if (t < K1) sc2[t] = sc2g[g * K1 + t];
    if (t >= K1 && t < 412) sc2[t] = -INFINITY;
    __syncthreads();

    if (t < K1) {
        float my = sc2[t];
        int r = 0;
        const float4* sc4 = (const float4*)sc2;
        #pragma unroll 4
        for (int j4 = 0; j4 < 103; ++j4) {
            float4 v = sc4[j4];
            int j = 4 * j4;
            r += (v.x > my) | ((v.x == my) & (j     < t));
            r += (v.y > my) | ((v.y == my) & (j + 1 < t));
            r += (v.z > my) | ((v.z == my) & (j + 2 < t));
            r += (v.w > my) | ((v.w == my) & (j + 3 < t));
        }
        rnk2[t] = r;
    }
    __syncthreads();

    float mx = -INFINITY, sm = 0.f;
    for (int n = wid; n < K1; n += 8) {
        if (rnk2[n] < K2) {
            float v = h2[((size_t)g * K1 + n) * DIM + lane] * sc2[n];
            mx = fmaxf(mx, v);
            sm += v;
        }
    }
    redmx[wid * DIM + lane] = mx;
    redsm[wid * DIM + lane] = sm;
    __syncthreads();
    if (wid == 0) {
        float m2 = redmx[lane], s2 = redsm[lane];
        #pragma unroll
        for (int w = 1; w < 8; ++w) {
            m2 = fmaxf(m2, redmx[w * DIM + lane]);
            s2 += redsm[w * DIM + lane];
        }
        zy[lane]       = x1buf[g * 2 * DIM + lane]       + m2;
        zy[DIM + lane] = x1buf[g * 2 * DIM + DIM + lane] + s2 * (1.0f / (float)K2);
    }
    __syncthreads();

    if (t < DIM) {
        float a = b1[t];
        #pragma unroll 8
        for (int j = 0; j < 2 * DIM; ++j) a += zy[j] * W1[j * DIM + t];
        zy[2 * DIM + t] = fmaxf(a, 0.f);
    }
    __syncthreads();
    if (t < OUTF) {
        float a = b2[t];
        #pragma unroll
        for (int j = 0; j < DIM; ++j) a += zy[2 * DIM + j] * W2[j * OUTF + t];
        out[g * OUTF + t] = a;
    }
}

// ---------------------------------------------------------------------------
extern "C" void kernel_launch(void* const* d_in, const int* in_sizes, int n_in,
                              void* d_out, int out_size, void* d_ws, size_t ws_size,
                              hipStream_t stream) {
    (void)in_sizes; (void)n_in; (void)out_size; (void)ws_size;
    const float* x       = (const float*)d_in[0];
    const int*   eidx    = (const int*)d_in[1];
    const float* c1_Wl   = (const float*)d_in[2];
    const float* c1_bl   = (const float*)d_in[3];
    const float* c1_Wr   = (const float*)d_in[4];
    const float* pool1_w = (const float*)d_in[5];
    const float* c2_Wl   = (const float*)d_in[6];
    const float* c2_bl   = (const float*)d_in[7];
    const float* c2_Wr   = (const float*)d_in[8];
    const float* pool2_w = (const float*)d_in[9];
    const float* lin1_W  = (const float*)d_in[10];
    const float* lin1_b  = (const float*)d_in[11];
    const float* lin2_W  = (const float*)d_in[12];
    const float* lin2_b  = (const float*)d_in[13];
    float* out = (float*)d_out;

    // Workspace layout (256-aligned), ~82 MB total
    char* w = (char*)d_ws;
    size_t off = 0;
    auto alloc = [&](size_t bytes) {
        void* p = w + off;
        off = (off + bytes + 255) & ~(size_t)255;
        return p;
    };
    float* h1p   = (float*)alloc((size_t)N1 * DIM * 4);        // 26.9 MB
    int*   invr  = (int*)  alloc((size_t)NN * 4);              // 512 KB
    float* x1buf = (float*)alloc((size_t)BGR * 2 * DIM * 4);   // 128 KB
    float* sc2g  = (float*)alloc((size_t)N1 * 4);              // 410 KB
    int*   indeg = (int*)  alloc((size_t)N1 * 4);              // 410 KB
    float* h2    = (float*)alloc((size_t)N1 * DIM * 4);        // 26.9 MB
    int*   csr   = (int*)  alloc((size_t)N1 * CSRW * 4);       // 26.9 MB

    hipMemsetAsync(indeg, 0, (size_t)N1 * 4, stream);

    stage1_kernel<<<BGR, 512, 0, stream>>>(x, eidx, c1_Wl, c1_bl, c1_Wr,
                                           pool1_w, h1p, invr, x1buf);
    csr_fill_kernel<<<EDG / 256, 256, 0, stream>>>(eidx, invr, csr, indeg);
    conv2_kernel<<<N1 / 32, 512, 0, stream>>>(h1p, csr, indeg, c2_Wl, c2_bl,
                                              c2_Wr, pool2_w, h2, sc2g);
    pool2_mlp_kernel<<<BGR, 512, 0, stream>>>(sc2g, h2, x1buf, lin1_W, lin1_b,
                                              lin2_W, lin2_b, out);
}

// Round 6
// 277.065 us; speedup vs baseline: 2.3320x; 1.0533x over previous
//
#include <hip/hip_runtime.h>
#include <hip/hip_bf16.h>

// Problem constants
#define BGR   256                 // graphs
#define NPG1  512                 // nodes per graph (input)
#define DEG   16
#define EPG   (NPG1 * DEG)        // 8192 edges per graph
#define LB    5                   // lookback features
#define DIM   64
#define OUTF  6
#define NN    (BGR * NPG1)        // 131,072
#define EDG   (BGR * EPG)         // 2,097,152
#define K1    410                 // ceil(0.8*512)
#define K2    328                 // ceil(0.8*410)
#define N1    (BGR * K1)          // 104,960
#define CSRW  64                  // CSR slots per node (max in-degree ~40)

// ---------------------------------------------------------------------------
// Stage 1 (one block per graph, 512 threads = 8 waves).
// Pass 1 uses lane=node (no cross-lane reduce, no per-node shfl chains).
__global__ __launch_bounds__(512)
void stage1_kernel(const float* __restrict__ x,
                   const int* __restrict__ eidx,
                   const float* __restrict__ Wl,
                   const float* __restrict__ bl,
                   const float* __restrict__ Wr,
                   const float* __restrict__ pw,
                   float* __restrict__ h1p,
                   int* __restrict__ invr,
                   float* __restrict__ x1buf) {
    __shared__ __align__(16) float xl[NPG1 * LB];
    __shared__ __align__(16) float sums[NPG1 * LB];
    __shared__ int   degi[NPG1];
    __shared__ __align__(16) float sc[NPG1];
    __shared__ int   rnk[NPG1];
    __shared__ float redmx[8 * DIM];
    __shared__ float redsm[8 * DIM];

    const int g = blockIdx.x, t = threadIdx.x;
    const int wid = t >> 6, lane = t & 63;
    const int* __restrict__ src = eidx;
    const int* __restrict__ dst = eidx + EDG;

    {
        const float4* x4 = (const float4*)(x + (size_t)g * (NPG1 * LB));
        float4* xl4 = (float4*)xl;
        float4* sm4 = (float4*)sums;
        const float4 z4 = make_float4(0.f, 0.f, 0.f, 0.f);
        #pragma unroll
        for (int k = 0; k < 2; ++k) {
            int i = k * 512 + t;
            if (i < NPG1 * LB / 4) { xl4[i] = x4[i]; sm4[i] = z4; }
        }
        degi[t] = 0;
    }
    __syncthreads();

    // Edge aggregation into LDS (native float LDS atomics)
    const int ebase = g * EPG;
    #pragma unroll 4
    for (int k = 0; k < EPG / 512; ++k) {
        int e = ebase + k * 512 + t;
        int s = src[e] & (NPG1 - 1);
        int d = dst[e] & (NPG1 - 1);
        #pragma unroll
        for (int j = 0; j < LB; ++j)
            unsafeAtomicAdd(&sums[d * LB + j], xl[s * LB + j]);
        atomicAdd(&degi[d], 1);
    }
    __syncthreads();

    // Pass 1 (lane = node): score for node n = wid*64 + lane.
    // Weights via wave-uniform loads (scalar cache), no LDS pipe, no shfl.
    {
        const int n = wid * 64 + lane;
        const float invd = 1.f / fmaxf((float)degi[n], 1.f);
        float m[LB], xv[LB];
        #pragma unroll
        for (int j = 0; j < LB; ++j) {
            m[j]  = sums[n * LB + j] * invd;     // stride-5: 2-way, free
            xv[j] = xl[n * LB + j];
        }
        const float4* Wl4 = (const float4*)Wl;
        const float4* Wr4 = (const float4*)Wr;
        const float4* bl4 = (const float4*)bl;
        const float4* pw4 = (const float4*)pw;
        float p = 0.f, q = 0.f;
        #pragma unroll 4
        for (int d4 = 0; d4 < DIM / 4; ++d4) {
            float4 bb = bl4[d4];
            float4 ww = pw4[d4];
            float4 h = bb;
            #pragma unroll
            for (int j = 0; j < LB; ++j) {
                float4 a = Wl4[j * (DIM / 4) + d4];
                float4 b = Wr4[j * (DIM / 4) + d4];
                h.x += m[j] * a.x + xv[j] * b.x;
                h.y += m[j] * a.y + xv[j] * b.y;
                h.z += m[j] * a.z + xv[j] * b.z;
                h.w += m[j] * a.w + xv[j] * b.w;
            }
            h.x = fmaxf(h.x, 0.f); h.y = fmaxf(h.y, 0.f);
            h.z = fmaxf(h.z, 0.f); h.w = fmaxf(h.w, 0.f);
            p += h.x * ww.x + h.y * ww.y + h.z * ww.z + h.w * ww.w;
            q += ww.x * ww.x + ww.y * ww.y + ww.z * ww.z + ww.w * ww.w;
        }
        sc[n] = tanhf(p / sqrtf(q));             // conflict-free write
    }
    __syncthreads();

    // Exact ranks (descending, ties -> lower index)
    {
        float my = sc[t];
        int r = 0;
        const float4* sc4 = (const float4*)sc;
        #pragma unroll 4
        for (int j4 = 0; j4 < NPG1 / 4; ++j4) {
            float4 v = sc4[j4];
            int j = 4 * j4;
            r += (v.x > my) | ((v.x == my) & (j     < t));
            r += (v.y > my) | ((v.y == my) & (j + 1 < t));
            r += (v.z > my) | ((v.z == my) & (j + 2 < t));
            r += (v.w > my) | ((v.w == my) & (j + 3 < t));
        }
        rnk[t] = r;
        invr[g * NPG1 + t] = (r < K1) ? r : -1;
    }
    __syncthreads();

    // Pass 2 (lane = dim): recompute kept rows, scaled coalesced writes,
    // readout accumulation. No shfl here.
    float wlv[LB], wrv[LB];
    #pragma unroll
    for (int j = 0; j < LB; ++j) { wlv[j] = Wl[j * DIM + lane]; wrv[j] = Wr[j * DIM + lane]; }
    const float blv = bl[lane];

    float mx = -INFINITY, sm = 0.f;
    for (int n = wid; n < NPG1; n += 8) {
        int r = rnk[n];
        if (r >= K1) continue;
        float invd = 1.f / fmaxf((float)degi[n], 1.f);
        float al = 0.f, ar = 0.f;
        #pragma unroll
        for (int j = 0; j < LB; ++j) {
            al += sums[n * LB + j] * wlv[j];
            ar += xl[n * LB + j] * wrv[j];
        }
        float acc = fmaxf(blv + al * invd + ar, 0.f);
        float v = acc * sc[n];
        h1p[((size_t)g * K1 + r) * DIM + lane] = v;
        mx = fmaxf(mx, v);
        sm += v;
    }
    redmx[wid * DIM + lane] = mx;
    redsm[wid * DIM + lane] = sm;
    __syncthreads();
    if (wid == 0) {
        float m2 = redmx[lane], s2 = redsm[lane];
        #pragma unroll
        for (int w = 1; w < 8; ++w) {
            m2 = fmaxf(m2, redmx[w * DIM + lane]);
            s2 += redsm[w * DIM + lane];
        }
        x1buf[g * 2 * DIM + lane]       = m2;
        x1buf[g * 2 * DIM + DIM + lane] = s2 * (1.0f / (float)K1);
    }
}

// ---------------------------------------------------------------------------
// CSR fill: edge-parallel, full occupancy.
__global__ __launch_bounds__(256)
void csr_fill_kernel(const int* __restrict__ eidx,
                     const int* __restrict__ invr,
                     int* __restrict__ csr,
                     int* __restrict__ indeg) {
    int e = blockIdx.x * 256 + threadIdx.x;       // grid = EDG/256 exact
    int s = eidx[e];
    int d = eidx[EDG + e];
    int rs = invr[s];
    int rd = invr[d];
    if ((rs | rd) < 0) return;                    // either dropped
    int g = s >> 9;                               // src = g*512 + local
    int gn = g * K1 + rd;                         // global pooled dst id
    int slot = atomicAdd(&indeg[gn], 1);
    csr[(size_t)gn * CSRW + slot] = g * K1 + rs;  // global pooled src id
}

// ---------------------------------------------------------------------------
// conv2 fused: 4 nodes per wave, 8 waves (32 nodes) per block; atomic-free
// register gather + mean, GEMV with LDS weights, h2 + score out.
__global__ __launch_bounds__(512)
void conv2_kernel(const float* __restrict__ h1p,
                  const int* __restrict__ csr,
                  const int* __restrict__ indeg,
                  const float* __restrict__ Wl,
                  const float* __restrict__ bl,
                  const float* __restrict__ Wr,
                  const float* __restrict__ pw,
                  float* __restrict__ h2,
                  float* __restrict__ sc2g) {
    __shared__ __align__(16) float wls[DIM * DIM];      // 16 KB
    __shared__ __align__(16) float wrs[DIM * DIM];      // 16 KB
    __shared__ __align__(16) float mstage[8][4][DIM];   // 8 KB

    const int t = threadIdx.x, wid = t >> 6, lane = t & 63;
    for (int i = t; i < DIM * DIM; i += 512) { wls[i] = Wl[i]; wrs[i] = Wr[i]; }

    const float blv = bl[lane], pwv = pw[lane];
    float qq = pwv * pwv;
    #pragma unroll
    for (int o = 32; o; o >>= 1) qq += __shfl_xor(qq, o);
    const float inv_nrm = 1.f / sqrtf(qq);

    const int n0 = (blockIdx.x * 8 + wid) * 4;    // grid = N1/32 exact
    const int nA = n0, nB = n0 + 1, nC = n0 + 2, nD = n0 + 3;

    int dgA = indeg[nA], dgB = indeg[nB], dgC = indeg[nC], dgD = indeg[nD];
    int dgmax = max(max(dgA, dgB), max(dgC, dgD));
    const int4* cA = (const int4*)&csr[(size_t)nA * CSRW];
    const int4* cB = (const int4*)&csr[(size_t)nB * CSRW];
    const int4* cC = (const int4*)&csr[(size_t)nC * CSRW];
    const int4* cD = (const int4*)&csr[(size_t)nD * CSRW];

    float aA = 0.f, aB = 0.f, aC = 0.f, aD = 0.f;
    for (int kc = 0; 4 * kc < dgmax; ++kc) {
        int4 iA = cA[kc], iB = cB[kc], iC = cC[kc], iD = cD[kc];
        int k0 = 4 * kc;
        #define GACC(acc, idv, kk, dg, nself)                              \
        {   int   _id = ((kk) < (dg)) ? (idv) : (nself);                   \
            float _v  = h1p[(size_t)_id * DIM + lane];                     \
            acc += ((kk) < (dg)) ? _v : 0.f; }
        GACC(aA, iA.x, k0,     dgA, nA) GACC(aA, iA.y, k0 + 1, dgA, nA)
        GACC(aA, iA.z, k0 + 2, dgA, nA) GACC(aA, iA.w, k0 + 3, dgA, nA)
        GACC(aB, iB.x, k0,     dgB, nB) GACC(aB, iB.y, k0 + 1, dgB, nB)
        GACC(aB, iB.z, k0 + 2, dgB, nB) GACC(aB, iB.w, k0 + 3, dgB, nB)
        GACC(aC, iC.x, k0,     dgC, nC) GACC(aC, iC.y, k0 + 1, dgC, nC)
        GACC(aC, iC.z, k0 + 2, dgC, nC) GACC(aC, iC.w, k0 + 3, dgC, nC)
        GACC(aD, iD.x, k0,     dgD, nD) GACC(aD, iD.y, k0 + 1, dgD, nD)
        GACC(aD, iD.z, k0 + 2, dgD, nD) GACC(aD, iD.w, k0 + 3, dgD, nD)
        #undef GACC
    }

    mstage[wid][0][lane] = aA * (1.f / fmaxf((float)dgA, 1.f));
    mstage[wid][1][lane] = aB * (1.f / fmaxf((float)dgB, 1.f));
    mstage[wid][2][lane] = aC * (1.f / fmaxf((float)dgC, 1.f));
    mstage[wid][3][lane] = aD * (1.f / fmaxf((float)dgD, 1.f));
    __syncthreads();   // weights staged (covers wls/wrs for all waves)

    const float4* mA = (const float4*)&mstage[wid][0][0];
    const float4* mB = (const float4*)&mstage[wid][1][0];
    const float4* mC = (const float4*)&mstage[wid][2][0];
    const float4* mD = (const float4*)&mstage[wid][3][0];
    const float4* xA = (const float4*)&h1p[(size_t)nA * DIM];
    const float4* xB = (const float4*)&h1p[(size_t)nB * DIM];
    const float4* xC = (const float4*)&h1p[(size_t)nC * DIM];
    const float4* xD = (const float4*)&h1p[(size_t)nD * DIM];

    float lA = 0.f, lB = 0.f, lC = 0.f, lD = 0.f;
    float rA = 0.f, rB = 0.f, rC = 0.f, rD = 0.f;
    #pragma unroll 2
    for (int j4 = 0; j4 < DIM / 4; ++j4) {
        const int jb = 4 * j4 * DIM + lane;
        float w0 = wls[jb],           w1 = wls[jb + DIM];
        float w2 = wls[jb + 2 * DIM], w3 = wls[jb + 3 * DIM];
        float u0 = wrs[jb],           u1 = wrs[jb + DIM];
        float u2 = wrs[jb + 2 * DIM], u3 = wrs[jb + 3 * DIM];
        float4 a = mA[j4], b = mB[j4], c = mC[j4], d = mD[j4];
        float4 p = xA[j4], s = xB[j4], e = xC[j4], f = xD[j4];
        lA += a.x * w0 + a.y * w1 + a.z * w2 + a.w * w3;
        lB += b.x * w0 + b.y * w1 + b.z * w2 + b.w * w3;
        lC += c.x * w0 + c.y * w1 + c.z * w2 + c.w * w3;
        lD += d.x * w0 + d.y * w1 + d.z * w2 + d.w * w3;
        rA += p.x * u0 + p.y * u1 + p.z * u2 + p.w * u3;
        rB += s.x * u0 + s.y * u1 + s.z * u2 + s.w * u3;
        rC += e.x * u0 + e.y * u1 + e.z * u2 + e.w * u3;
        rD += f.x * u0 + f.y * u1 + f.z * u2 + f.w * u3;
    }
    float hA = fmaxf(blv + lA + rA, 0.f);
    float hB = fmaxf(blv + lB + rB, 0.f);
    float hC = fmaxf(blv + lC + rC, 0.f);
    float hD = fmaxf(blv + lD + rD, 0.f);
    h2[(size_t)nA * DIM + lane] = hA;
    h2[(size_t)nB * DIM + lane] = hB;
    h2[(size_t)nC * DIM + lane] = hC;
    h2[(size_t)nD * DIM + lane] = hD;
    float pA = hA * pwv, pB = hB * pwv, pC = hC * pwv, pD = hD * pwv;
    #pragma unroll
    for (int o = 32; o; o >>= 1) {
        pA += __shfl_xor(pA, o); pB += __shfl_xor(pB, o);
        pC += __shfl_xor(pC, o); pD += __shfl_xor(pD, o);
    }
    if (lane == 0) {
        sc2g[nA] = tanhf(pA * inv_nrm);
        sc2g[nB] = tanhf(pB * inv_nrm);
        sc2g[nC] = tanhf(pC * inv_nrm);
        sc2g[nD] = tanhf(pD * inv_nrm);
    }
}

// ---------------------------------------------------------------------------
// Pool2 + readout2 + final MLP (one block per graph).
__global__ __launch_bounds__(512)
void pool2_mlp_kernel(const float* __restrict__ sc2g,
                      const float* __restrict__ h2,
                      const float* __restrict__ x1buf,
                      const float* __restrict__ W1,
                      const float* __restrict__ b1,
                      const float* __restrict__ W2,
                      const float* __restrict__ b2,
                      float* __restrict__ out) {
    __shared__ __align__(16) float sc2[412];
    __shared__ int   rnk2[K1];
    __shared__ float redmx[8 * DIM];
    __shared__ float redsm[8 * DIM];
    __shared__ float zy[2 * DIM + DIM];

    const int g = blockIdx.x, t = threadIdx.x;
    const int wid = t >> 6, lane = t & 63;

    if (t < K1) sc2[t] = sc2g[g * K1 + t];
    if (t >= K1 && t < 412) sc2[t] = -INFINITY;
    __syncthreads();

    if (t < K1) {
        float my = sc2[t];
        int r = 0;
        const float4* sc4 = (const float4*)sc2;
        #pragma unroll 4
        for (int j4 = 0; j4 < 103; ++j4) {
            float4 v = sc4[j4];
            int j = 4 * j4;
            r += (v.x > my) | ((v.x == my) & (j     < t));
            r += (v.y > my) | ((v.y == my) & (j + 1 < t));
            r += (v.z > my) | ((v.z == my) & (j + 2 < t));
            r += (v.w > my) | ((v.w == my) & (j + 3 < t));
        }
        rnk2[t] = r;
    }
    __syncthreads();

    float mx = -INFINITY, sm = 0.f;
    for (int n = wid; n < K1; n += 8) {
        if (rnk2[n] < K2) {
            float v = h2[((size_t)g * K1 + n) * DIM + lane] * sc2[n];
            mx = fmaxf(mx, v);
            sm += v;
        }
    }
    redmx[wid * DIM + lane] = mx;
    redsm[wid * DIM + lane] = sm;
    __syncthreads();
    if (wid == 0) {
        float m2 = redmx[lane], s2 = redsm[lane];
        #pragma unroll
        for (int w = 1; w < 8; ++w) {
            m2 = fmaxf(m2, redmx[w * DIM + lane]);
            s2 += redsm[w * DIM + lane];
        }
        zy[lane]       = x1buf[g * 2 * DIM + lane]       + m2;
        zy[DIM + lane] = x1buf[g * 2 * DIM + DIM + lane] + s2 * (1.0f / (float)K2);
    }
    __syncthreads();

    if (t < DIM) {
        float a = b1[t];
        #pragma unroll 8
        for (int j = 0; j < 2 * DIM; ++j) a += zy[j] * W1[j * DIM + t];
        zy[2 * DIM + t] = fmaxf(a, 0.f);
    }
    __syncthreads();
    if (t < OUTF) {
        float a = b2[t];
        #pragma unroll
        for (int j = 0; j < DIM; ++j) a += zy[2 * DIM + j] * W2[j * OUTF + t];
        out[g * OUTF + t] = a;
    }
}

// ---------------------------------------------------------------------------
extern "C" void kernel_launch(void* const* d_in, const int* in_sizes, int n_in,
                              void* d_out, int out_size, void* d_ws, size_t ws_size,
                              hipStream_t stream) {
    (void)in_sizes; (void)n_in; (void)out_size; (void)ws_size;
    const float* x       = (const float*)d_in[0];
    const int*   eidx    = (const int*)d_in[1];
    const float* c1_Wl   = (const float*)d_in[2];
    const float* c1_bl   = (const float*)d_in[3];
    const float* c1_Wr   = (const float*)d_in[4];
    const float* pool1_w = (const float*)d_in[5];
    const float* c2_Wl   = (const float*)d_in[6];
    const float* c2_bl   = (const float*)d_in[7];
    const float* c2_Wr   = (const float*)d_in[8];
    const float* pool2_w = (const float*)d_in[9];
    const float* lin1_W  = (const float*)d_in[10];
    const float* lin1_b  = (const float*)d_in[11];
    const float* lin2_W  = (const float*)d_in[12];
    const float* lin2_b  = (const float*)d_in[13];
    float* out = (float*)d_out;

    // Workspace layout (256-aligned), ~82 MB total
    char* w = (char*)d_ws;
    size_t off = 0;
    auto alloc = [&](size_t bytes) {
        void* p = w + off;
        off = (off + bytes + 255) & ~(size_t)255;
        return p;
    };
    float* h1p   = (float*)alloc((size_t)N1 * DIM * 4);        // 26.9 MB
    int*   invr  = (int*)  alloc((size_t)NN * 4);              // 512 KB
    float* x1buf = (float*)alloc((size_t)BGR * 2 * DIM * 4);   // 128 KB
    float* sc2g  = (float*)alloc((size_t)N1 * 4);              // 410 KB
    int*   indeg = (int*)  alloc((size_t)N1 * 4);              // 410 KB
    float* h2    = (float*)alloc((size_t)N1 * DIM * 4);        // 26.9 MB
    int*   csr   = (int*)  alloc((size_t)N1 * CSRW * 4);       // 26.9 MB

    hipMemsetAsync(indeg, 0, (size_t)N1 * 4, stream);

    stage1_kernel<<<BGR, 512, 0, stream>>>(x, eidx, c1_Wl, c1_bl, c1_Wr,
                                           pool1_w, h1p, invr, x1buf);
    csr_fill_kernel<<<EDG / 256, 256, 0, stream>>>(eidx, invr, csr, indeg);
    conv2_kernel<<<N1 / 32, 512, 0, stream>>>(h1p, csr, indeg, c2_Wl, c2_bl,
                                              c2_Wr, pool2_w, h2, sc2g);
    pool2_mlp_kernel<<<BGR, 512, 0, stream>>>(sc2g, h2, x1buf, lin1_W, lin1_b,
                                              lin2_W, lin2_b, out);
}